// Round 1
// baseline (1419.657 us; speedup 1.0000x reference)
//
#include <hip/hip_runtime.h>

// LightweightMultiHeadAttention on MI355X.
// Algebraic collapse: scores[h,b,s] = q_eff[h] . v[b,s] + q_bias[h], where
//   q_eff[h][c]  = sum_j Q[h][j] * Wk[h*8+j][c] / sqrt(8)   (precomputed, 16x256)
//   q_bias[h]    = sum_j Q[h][j] * bk[h*8+j]    / sqrt(8)
// Then one fused kernel per batch: load v[b] (60x256) once into LDS (transposed),
// scores via SGPR-held q_eff, wave-butterfly softmax, PV from LDS, coalesced store.

#define SS   60
#define DIN  256
#define NH   16

__global__ void prep_kernel(const float* __restrict__ Q, const float* __restrict__ Wk,
                            const float* __restrict__ bk, float* __restrict__ ws) {
    int i = blockIdx.x * 256 + threadIdx.x;     // 0..4095
    if (i >= NH * DIN) return;
    const float scale = 0.35355339059327379f;   // 1/sqrt(8)
    int c = i >> 4, h = i & 15;
    float acc = 0.f;
    #pragma unroll
    for (int j = 0; j < 8; ++j)
        acc = fmaf(Q[h * 8 + j], Wk[(size_t)(h * 8 + j) * DIN + c], acc);
    ws[(c << 4) + h] = acc * scale;             // q_eff transposed: [c][h]
    if (i < NH) {
        float bb = 0.f;
        #pragma unroll
        for (int j = 0; j < 8; ++j) bb = fmaf(Q[i * 8 + j], bk[i * 8 + j], bb);
        ws[NH * DIN + i] = bb * scale;          // q_bias[h]
    }
}

__global__ __launch_bounds__(256) void attn_kernel(
        const float* __restrict__ v, const unsigned char* __restrict__ pm,
        const float* __restrict__ ws, float* __restrict__ out,
        float* __restrict__ attn, long long nBS) {
    // v_t is transposed: v_t[c][s], row stride SS. +4 slack: pass-1 lanes 60..63
    // read garbage (scores masked to -1e30 later), keep them in-bounds.
    __shared__ float v_t[DIN * SS + 4];
    __shared__ float p_t[NH * SS];

    const int t = threadIdx.x;
    const int b = blockIdx.x;
    const float* vb = v + (size_t)b * (SS * DIN);

    // ---- load + transpose: global coalesced (lane = channel), LDS write stride SS ----
    #pragma unroll 10
    for (int s = 0; s < SS; ++s)
        v_t[t * SS + s] = vb[s * DIN + t];
    __syncthreads();

    // ---- pass 1: scores. lane = s, wave w covers h0 = 4w .. 4w+3 ----
    const int sl = t & 63;
    const int h0 = __builtin_amdgcn_readfirstlane((t >> 6) << 2);
    const float* qT = ws;                 // [c][16]
    const float* qb = ws + NH * DIN;      // [16]
    float a0 = qb[h0 + 0], a1 = qb[h0 + 1], a2 = qb[h0 + 2], a3 = qb[h0 + 3];
    #pragma unroll 8
    for (int c = 0; c < DIN; ++c) {
        float vv = v_t[c * SS + sl];                                   // stride-1 in lane: conflict-free
        float4 q4 = *reinterpret_cast<const float4*>(qT + (c << 4) + h0); // wave-uniform -> s_load_dwordx4
        a0 = fmaf(q4.x, vv, a0);
        a1 = fmaf(q4.y, vv, a1);
        a2 = fmaf(q4.z, vv, a2);
        a3 = fmaf(q4.w, vv, a3);
    }

    // ---- softmax over s (64-lane butterflies), write p to LDS + attn to global ----
    float sc[4] = {a0, a1, a2, a3};
    const bool in = sl < SS;
    bool masked = false;
    if (in) masked = (pm[(size_t)b * SS + sl] != 0);
    #pragma unroll
    for (int j = 0; j < 4; ++j) {
        float s = sc[j];
        if (!in) s = -1e30f;          // pad lanes: exp -> 0
        else if (masked) s = -1e6f;   // exact reference semantics
        float m = s;
        #pragma unroll
        for (int off = 32; off > 0; off >>= 1)
            m = fmaxf(m, __shfl_xor(m, off));
        float e = expf(s - m);
        float sum = e;
        #pragma unroll
        for (int off = 32; off > 0; off >>= 1)
            sum += __shfl_xor(sum, off);
        float p = e / sum;
        if (in) {
            p_t[(h0 + j) * SS + sl] = p;
            attn[(size_t)(h0 + j) * nBS + (size_t)b * SS + sl] = p;
        }
    }
    __syncthreads();

    // ---- pass 2: out[b, h, d] = sum_s p[h][s] * v[b, s, h*16+d]; channel = t ----
    const int hh = t >> 4;
    const float* vrow = v_t + t * SS;     // stride-60 per lane: 8-way conflict, accepted
    const float* prow = p_t + hh * SS;    // 16-lane broadcast
    float acc = 0.f;
    #pragma unroll 10
    for (int s = 0; s < SS; ++s)
        acc = fmaf(prow[s], vrow[s], acc);
    out[(size_t)b * DIN + t] = acc;
}

extern "C" void kernel_launch(void* const* d_in, const int* in_sizes, int n_in,
                              void* d_out, int out_size, void* d_ws, size_t ws_size,
                              hipStream_t stream) {
    const float* v            = (const float*)d_in[0];
    const float* Q            = (const float*)d_in[1];
    const float* Wk           = (const float*)d_in[2];
    const float* bk           = (const float*)d_in[3];
    const unsigned char* pm   = (const unsigned char*)d_in[4];
    float* ws   = (float*)d_ws;          // needs (16*256 + 16)*4 = 16448 bytes
    float* out  = (float*)d_out;
    const int B = in_sizes[0] / (SS * DIN);
    float* attn = out + (size_t)B * DIN; // second tuple output, concatenated flat

    prep_kernel<<<(NH * DIN + 255) / 256, 256, 0, stream>>>(Q, Wk, bk, ws);
    attn_kernel<<<B, 256, 0, stream>>>(v, pm, ws, out, attn, (long long)B * SS);
}